// Round 21
// baseline (62.391 us; speedup 1.0000x reference)
//
#include <hip/hip_runtime.h>

#define FLT_BIG 3.402823466e38f

// tie-break matches jax.lax.top_k: higher value wins; equal values -> lower index wins
static __device__ __forceinline__ bool better(float v1, int i1, float v2, int i2) {
  return (v1 > v2) || ((v1 == v2) && (i1 < i2));
}

// XCD-aware bijective swizzle (8 XCDs; grid divisible by 8): consecutive logical
// blocks land on the SAME XCD -> shared kmT[h] / K tiles become L2 hits.
static __device__ __forceinline__ int xcd_swizzle(int nblocks) {
  const int bid = blockIdx.x;
  const int chunk = nblocks >> 3;           // blocks per XCD
  return (bid & 7) * chunk + (bid >> 3);
}

// kmT[h][e][n] = mean_j x[(n*32+j)*256 + h*32+e]  (transposed: ball is the fast axis)
__global__ void kmeanT_kernel(const float* __restrict__ x, float* __restrict__ kmT) {
  const int n = blockIdx.x;        // ball
  const int t = threadIdx.x;       // h*32+e
  const float* base = x + n * 32 * 256 + t;
  float acc = 0.f;
  #pragma unroll
  for (int j = 0; j < 32; ++j) acc += base[j * 256];
  const int h = t >> 5, e = t & 31;
  kmT[h * 8192 + e * 256 + n] = acc * (1.0f / 32.0f);
}

// Fused select+attn, block = (h, 32 queries) = one ball's members.
//  P1: sim GEMM (coalesced kmT float4, reg ping-pong, LDS-broadcast q)
//  P2/P3: FOUR 8-query quarter-passes through an [8][264] simbuf. Total LDS
//      12.8 KB -> 8 blocks/CU (= wave-slot limit at VGPR 64) -> the 2048-block
//      grid is fully resident in ONE generation. r19/r20 at 21 KB fit only 7,
//      leaving a 1-block straggler generation per CU (occupancy up, time flat).
//      Scan uses stride-32 scalar reads (bank = ch, conflict-free; ascending
//      index j = ch+32i preserves the exact tie-break) + 5-stage shfl merge.
//  P4: attn per query (r11-proven body): K fragments double as V; a ball's 32
//      queries select nearly identical top-2 -> K tiles L1-hot after first iter.
// Mask provably all-true (topv2 >> 1e-10); softmax without max shift (|logit|<~5).
__global__ __launch_bounds__(256) void fused_kernel(const float* __restrict__ x,
                                                    const float* __restrict__ kmT,
                                                    float* __restrict__ out) {
  __shared__ float qtile[32 * 32];      // 4096 B, persistent through P4
  __shared__ float simbuf[8 * 264];     // 8448 B, reused per quarter
  __shared__ int2 selbuf[32];           // 256 B          -> total 12.8 KB
  const int vb = xcd_swizzle(2048);     // 2048 blocks = 8 heads x 256 q-groups
  const int h = vb >> 8;
  const int qg = vb & 255;
  const int t = threadIdx.x;
  const int w = t >> 6, lane = t & 63;

  // ---- stage 32 q-rows (coalesced, 8 lanes/row) ----
  {
    const int r = t >> 3, c = t & 7;
    *(float4*)&qtile[r * 32 + c * 4] =
        *(const float4*)(x + (qg * 32 + r) * 256 + h * 32 + c * 4);
  }
  __syncthreads();

  // ---- P1: GEMM acc[qq][j] = q[w*8+qq] . km[4*lane+j] ----
  const float4* kmp = (const float4*)(kmT + h * 8192);   // [32 e][64 float4 over balls]
  float acc[8][4];
  #pragma unroll
  for (int qq = 0; qq < 8; ++qq)
    #pragma unroll
    for (int j = 0; j < 4; ++j) acc[qq][j] = 0.f;

  {
    float4 ka[4], kb[4];
    #pragma unroll
    for (int d = 0; d < 4; ++d) ka[d] = kmp[d * 64 + lane];

    #pragma unroll
    for (int e0 = 0; e0 < 8; ++e0) {               // e0 constant per unrolled iter
      float4* cur = (e0 & 1) ? kb : ka;
      float4* nxt = (e0 & 1) ? ka : kb;
      if (e0 < 7) {
        #pragma unroll
        for (int d = 0; d < 4; ++d) nxt[d] = kmp[((e0 + 1) * 4 + d) * 64 + lane];
      }
      #pragma unroll
      for (int qq = 0; qq < 8; ++qq) {
        const float4 qf = *(const float4*)&qtile[(w * 8 + qq) * 32 + e0 * 4];  // uniform
        acc[qq][0] = fmaf(qf.w, cur[3].x, fmaf(qf.z, cur[2].x, fmaf(qf.y, cur[1].x, fmaf(qf.x, cur[0].x, acc[qq][0]))));
        acc[qq][1] = fmaf(qf.w, cur[3].y, fmaf(qf.z, cur[2].y, fmaf(qf.y, cur[1].y, fmaf(qf.x, cur[0].y, acc[qq][1]))));
        acc[qq][2] = fmaf(qf.w, cur[3].z, fmaf(qf.z, cur[2].z, fmaf(qf.y, cur[1].z, fmaf(qf.x, cur[0].z, acc[qq][2]))));
        acc[qq][3] = fmaf(qf.w, cur[3].w, fmaf(qf.z, cur[2].w, fmaf(qf.y, cur[1].w, fmaf(qf.x, cur[0].w, acc[qq][3]))));
      }
    }
  }

  // ---- P2/P3: four 8-query quarters through simbuf ----
  #pragma unroll
  for (int qtr = 0; qtr < 4; ++qtr) {
    __syncthreads();   // simbuf free (prev quarter's scans complete)
    if (w == qtr) {
      #pragma unroll
      for (int qq = 0; qq < 8; ++qq) {
        *(float4*)&simbuf[qq * 264 + lane * 4] =
            make_float4(acc[qq][0], acc[qq][1], acc[qq][2], acc[qq][3]);
      }
    }
    __syncthreads();

    // scan: thread (row = t>>5, ch = t&31) reads j = ch + 32*i (bank=ch: no conflict)
    const int row = t >> 5, ch = t & 31;
    const float* rowp = &simbuf[row * 264];
    float a1 = -FLT_BIG, a2 = -FLT_BIG;
    int j1 = 0, j2 = 0;
    #pragma unroll
    for (int i = 0; i < 8; ++i) {
      const int idx = ch + 32 * i;               // ascending: strict > is tie-exact
      const float v = rowp[idx];
      if (v > a1) { a2 = a1; j2 = j1; a1 = v; j1 = idx; }
      else if (v > a2) { a2 = v; j2 = idx; }
    }

    int pk = j1 | (j2 << 16);
    #pragma unroll
    for (int m = 1; m <= 16; m <<= 1) {          // 5-stage merge within 32-lane group
      const float b1 = __shfl_xor(a1, m);
      const float b2 = __shfl_xor(a2, m);
      const int bpk = __shfl_xor(pk, m);
      const int bj1 = bpk & 65535, bj2 = bpk >> 16;
      int c1 = pk & 65535, c2 = pk >> 16;
      if (better(b1, bj1, a1, c1)) {
        if (better(a1, c1, b2, bj2)) { a2 = a1; c2 = c1; } else { a2 = b2; c2 = bj2; }
        a1 = b1; c1 = bj1;
      } else if (better(b1, bj1, a2, c2)) { a2 = b1; c2 = bj1; }
      pk = c1 | (c2 << 16);
    }
    if (ch == 0) selbuf[qtr * 8 + row] = make_int2(pk & 65535, pk >> 16);
  }
  __syncthreads();   // selbuf visible to all waves

  // ---- P4: attention; wave w handles queries w*8..w*8+7 (r11-proven body) ----
  const int o = lane & 7;
  const int ro = lane >> 3;
  #pragma unroll 2
  for (int qq = 0; qq < 8; ++qq) {
    const int qloc = w * 8 + qq;
    const int2 sv = selbuf[qloc];              // wave-uniform LDS read
    const int bA = sv.x, bB = sv.y;
    const float4 qf = *(const float4*)&qtile[qloc * 32 + o * 4];

    float4 kA[4], kB[4];
    const float* xa = x + bA * 8192 + ro * 256 + h * 32 + o * 4;
    const float* xb = x + bB * 8192 + ro * 256 + h * 32 + o * 4;
    #pragma unroll
    for (int i = 0; i < 4; ++i) {
      kA[i] = *(const float4*)(xa + i * 2048);
      kB[i] = *(const float4*)(xb + i * 2048);
    }

    float dA[4], dB[4];
    #pragma unroll
    for (int i = 0; i < 4; ++i) {
      float a = qf.x * kA[i].x; a = fmaf(qf.y, kA[i].y, a);
      a = fmaf(qf.z, kA[i].z, a); a = fmaf(qf.w, kA[i].w, a);
      dA[i] = a;
      float b = qf.x * kB[i].x; b = fmaf(qf.y, kB[i].y, b);
      b = fmaf(qf.z, kB[i].z, b); b = fmaf(qf.w, kB[i].w, b);
      dB[i] = b;
    }
    #pragma unroll
    for (int m = 1; m <= 4; m <<= 1) {
      #pragma unroll
      for (int i = 0; i < 4; ++i) {
        dA[i] += __shfl_xor(dA[i], m);
        dB[i] += __shfl_xor(dB[i], m);
      }
    }

    float pA[4], pB[4], psum = 0.f;
    #pragma unroll
    for (int i = 0; i < 4; ++i) {
      pA[i] = __expf(dA[i] * 0.0625f);
      pB[i] = __expf(dB[i] * 0.0625f);
      psum += pA[i] + pB[i];
    }
    #pragma unroll
    for (int m = 8; m <= 32; m <<= 1) psum += __shfl_xor(psum, m);

    float ox = 0.f, oy = 0.f, oz = 0.f, ow = 0.f;
    #pragma unroll
    for (int i = 0; i < 4; ++i) {
      ox = fmaf(pA[i], kA[i].x, ox); oy = fmaf(pA[i], kA[i].y, oy);
      oz = fmaf(pA[i], kA[i].z, oz); ow = fmaf(pA[i], kA[i].w, ow);
      ox = fmaf(pB[i], kB[i].x, ox); oy = fmaf(pB[i], kB[i].y, oy);
      oz = fmaf(pB[i], kB[i].z, oz); ow = fmaf(pB[i], kB[i].w, ow);
    }
    #pragma unroll
    for (int m = 8; m <= 32; m <<= 1) {
      ox += __shfl_xor(ox, m);
      oy += __shfl_xor(oy, m);
      oz += __shfl_xor(oz, m);
      ow += __shfl_xor(ow, m);
    }

    const float inv = 1.0f / psum;
    if (ro == 0) {
      *(float4*)(out + (qg * 32 + qloc) * 256 + h * 32 + o * 4) =
          make_float4(ox * inv, oy * inv, oz * inv, ow * inv);
    }
  }
}

extern "C" void kernel_launch(void* const* d_in, const int* in_sizes, int n_in,
                              void* d_out, int out_size, void* d_ws, size_t ws_size,
                              hipStream_t stream) {
  const float* x = (const float*)d_in[0];   // (8192, 256) fp32; pos (d_in[1]) is dead code
  float* kmT = (float*)d_ws;                // 256 KB
  float* out = (float*)d_out;

  kmeanT_kernel<<<256, 256, 0, stream>>>(x, kmT);
  fused_kernel<<<2048, 256, 0, stream>>>(x, kmT, out);
}

// Round 22
// 57.717 us; speedup vs baseline: 1.0810x; 1.0810x over previous
//
#include <hip/hip_runtime.h>

#define FLT_BIG 3.402823466e38f

// tie-break matches jax.lax.top_k: higher value wins; equal values -> lower index wins
static __device__ __forceinline__ bool better(float v1, int i1, float v2, int i2) {
  return (v1 > v2) || ((v1 == v2) && (i1 < i2));
}

// XCD-aware bijective swizzle (8 XCDs; grid divisible by 8): consecutive logical
// blocks land on the SAME XCD -> shared kmT[h] / K tiles become L2 hits.
static __device__ __forceinline__ int xcd_swizzle(int nblocks) {
  const int bid = blockIdx.x;
  const int chunk = nblocks >> 3;           // blocks per XCD
  return (bid & 7) * chunk + (bid >> 3);
}

// kmT[h][e][n] = mean_j x[(n*32+j)*256 + h*32+e]  (transposed: ball is the fast axis)
// v2: lane = (h, e-quad) -> float4 loads cover a full 1KB row per wave-instr
// (8 lines/instr, 4x fewer load instructions than the scalar version); the 32
// member rows are split across 4 waves with an LDS partial reduce.
__global__ __launch_bounds__(256) void kmeanT_kernel(const float* __restrict__ x,
                                                     float* __restrict__ kmT) {
  __shared__ float4 part[4][64];
  const int n = blockIdx.x;            // ball
  const int t = threadIdx.x;
  const int w = t >> 6, lane = t & 63;
  const int h = lane >> 3, e4 = lane & 7;

  const float* base = x + n * 32 * 256 + h * 32 + e4 * 4;
  float4 a = make_float4(0.f, 0.f, 0.f, 0.f);
  #pragma unroll
  for (int j = 0; j < 8; ++j) {
    const float4 v = *(const float4*)(base + (w * 8 + j) * 256);
    a.x += v.x; a.y += v.y; a.z += v.z; a.w += v.w;
  }
  part[w][lane] = a;
  __syncthreads();

  if (t < 64) {
    float4 s = part[0][t];
    #pragma unroll
    for (int k = 1; k < 4; ++k) {
      const float4 v = part[k][t];
      s.x += v.x; s.y += v.y; s.z += v.z; s.w += v.w;
    }
    const int hh = t >> 3, ee = (t & 7) * 4;
    kmT[hh * 8192 + (ee + 0) * 256 + n] = s.x * (1.0f / 32.0f);
    kmT[hh * 8192 + (ee + 1) * 256 + n] = s.y * (1.0f / 32.0f);
    kmT[hh * 8192 + (ee + 2) * 256 + n] = s.z * (1.0f / 32.0f);
    kmT[hh * 8192 + (ee + 3) * 256 + n] = s.w * (1.0f / 32.0f);
  }
}

// Fused select+attn (r18-proven best: 57.3us), block = (h, 32 queries) = one ball.
//  P1: sim GEMM (coalesced kmT float4, reg ping-pong, LDS-broadcast q)
//  P2: sim tile -> simbuf LDS (register-disjoint hand-off; acc dies here)
//  P3: LDS top-2 scan + 3-stage shfl merge; result stays in a register (pk)
//  P4: attn per query: K fragments double as V; a ball's 32 queries select nearly
//      identical top-2 -> K tiles L1-hot after the first iteration.
// Mask provably all-true (topv2 >> 1e-10); softmax without max shift (|logit|<~5).
__global__ __launch_bounds__(256) void fused_kernel(const float* __restrict__ x,
                                                    const float* __restrict__ kmT,
                                                    float* __restrict__ out) {
  __shared__ float qtile[32 * 32];      // 4 KB, persistent through P4
  __shared__ float simbuf[32 * 260];    // 33.3 KB
  const int vb = xcd_swizzle(2048);     // 2048 blocks = 8 heads x 256 q-groups
  const int h = vb >> 8;
  const int qg = vb & 255;
  const int t = threadIdx.x;
  const int w = t >> 6, lane = t & 63;

  // ---- stage 32 q-rows (coalesced, 8 lanes/row) ----
  {
    const int r = t >> 3, c = t & 7;
    *(float4*)&qtile[r * 32 + c * 4] =
        *(const float4*)(x + (qg * 32 + r) * 256 + h * 32 + c * 4);
  }
  __syncthreads();

  // ---- P1: GEMM acc[qq][j] = q[w*8+qq] . km[4*lane+j] ----
  const float4* kmp = (const float4*)(kmT + h * 8192);   // [32 e][64 float4 over balls]
  float acc[8][4];
  #pragma unroll
  for (int qq = 0; qq < 8; ++qq)
    #pragma unroll
    for (int j = 0; j < 4; ++j) acc[qq][j] = 0.f;

  {
    float4 ka[4], kb[4];
    #pragma unroll
    for (int d = 0; d < 4; ++d) ka[d] = kmp[d * 64 + lane];

    #pragma unroll
    for (int e0 = 0; e0 < 8; ++e0) {               // e0 constant per unrolled iter
      float4* cur = (e0 & 1) ? kb : ka;
      float4* nxt = (e0 & 1) ? ka : kb;
      if (e0 < 7) {
        #pragma unroll
        for (int d = 0; d < 4; ++d) nxt[d] = kmp[((e0 + 1) * 4 + d) * 64 + lane];
      }
      #pragma unroll
      for (int qq = 0; qq < 8; ++qq) {
        const float4 qf = *(const float4*)&qtile[(w * 8 + qq) * 32 + e0 * 4];  // uniform
        acc[qq][0] = fmaf(qf.w, cur[3].x, fmaf(qf.z, cur[2].x, fmaf(qf.y, cur[1].x, fmaf(qf.x, cur[0].x, acc[qq][0]))));
        acc[qq][1] = fmaf(qf.w, cur[3].y, fmaf(qf.z, cur[2].y, fmaf(qf.y, cur[1].y, fmaf(qf.x, cur[0].y, acc[qq][1]))));
        acc[qq][2] = fmaf(qf.w, cur[3].z, fmaf(qf.z, cur[2].z, fmaf(qf.y, cur[1].z, fmaf(qf.x, cur[0].z, acc[qq][2]))));
        acc[qq][3] = fmaf(qf.w, cur[3].w, fmaf(qf.z, cur[2].w, fmaf(qf.y, cur[1].w, fmaf(qf.x, cur[0].w, acc[qq][3]))));
      }
    }
  }

  // ---- P2: sim tile (compare-only) -> simbuf [32][260]; acc dies here ----
  #pragma unroll
  for (int qq = 0; qq < 8; ++qq) {
    *(float4*)&simbuf[(w * 8 + qq) * 260 + lane * 4] =
        make_float4(acc[qq][0], acc[qq][1], acc[qq][2], acc[qq][3]);
  }
  __syncthreads();

  // ---- P3: top-2 scan (thread = (qloc = t>>3, ch = t&7), 32 values) + merge ----
  int pk;
  {
    const int qloc = t >> 3, ch = t & 7;
    const float* rowp = &simbuf[qloc * 260 + ch * 32];
    float a1 = -FLT_BIG, a2 = -FLT_BIG;
    int j1 = 0, j2 = 0;
    #pragma unroll
    for (int i = 0; i < 8; ++i) {
      const float4 v4 = *(const float4*)(rowp + i * 4);
      const int b0 = ch * 32 + i * 4;
      // ascending-index scan: strict > is tie-exact (later index loses ties)
      if (v4.x > a1) { a2 = a1; j2 = j1; a1 = v4.x; j1 = b0; }
      else if (v4.x > a2) { a2 = v4.x; j2 = b0; }
      if (v4.y > a1) { a2 = a1; j2 = j1; a1 = v4.y; j1 = b0 + 1; }
      else if (v4.y > a2) { a2 = v4.y; j2 = b0 + 1; }
      if (v4.z > a1) { a2 = a1; j2 = j1; a1 = v4.z; j1 = b0 + 2; }
      else if (v4.z > a2) { a2 = v4.z; j2 = b0 + 2; }
      if (v4.w > a1) { a2 = a1; j2 = j1; a1 = v4.w; j1 = b0 + 3; }
      else if (v4.w > a2) { a2 = v4.w; j2 = b0 + 3; }
    }

    pk = j1 | (j2 << 16);
    #pragma unroll
    for (int m = 1; m <= 4; m <<= 1) {
      const float b1 = __shfl_xor(a1, m);
      const float b2 = __shfl_xor(a2, m);
      const int bpk = __shfl_xor(pk, m);
      const int bj1 = bpk & 65535, bj2 = bpk >> 16;
      int c1 = pk & 65535, c2 = pk >> 16;
      if (better(b1, bj1, a1, c1)) {
        if (better(a1, c1, b2, bj2)) { a2 = a1; c2 = c1; } else { a2 = b2; c2 = bj2; }
        a1 = b1; c1 = bj1;
      } else if (better(b1, bj1, a2, c2)) { a2 = b1; c2 = bj1; }
      pk = c1 | (c2 << 16);
    }
    // after the butterfly all 8 ch-lanes of query qloc hold the merged pk
  }

  // ---- P4: attention; wave w handles queries w*8..w*8+7 (r11-proven body) ----
  const int o = lane & 7;
  const int ro = lane >> 3;
  #pragma unroll 1
  for (int qq = 0; qq < 8; ++qq) {
    const int qloc = w * 8 + qq;
    const int pkq = __shfl(pk, qq * 8);        // broadcast query qq's top-2
    const int bA = pkq & 65535, bB = pkq >> 16;
    const float4 qf = *(const float4*)&qtile[qloc * 32 + o * 4];

    float4 kA[4], kB[4];
    const float* xa = x + bA * 8192 + ro * 256 + h * 32 + o * 4;
    const float* xb = x + bB * 8192 + ro * 256 + h * 32 + o * 4;
    #pragma unroll
    for (int i = 0; i < 4; ++i) {
      kA[i] = *(const float4*)(xa + i * 2048);
      kB[i] = *(const float4*)(xb + i * 2048);
    }

    float dA[4], dB[4];
    #pragma unroll
    for (int i = 0; i < 4; ++i) {
      float a = qf.x * kA[i].x; a = fmaf(qf.y, kA[i].y, a);
      a = fmaf(qf.z, kA[i].z, a); a = fmaf(qf.w, kA[i].w, a);
      dA[i] = a;
      float b = qf.x * kB[i].x; b = fmaf(qf.y, kB[i].y, b);
      b = fmaf(qf.z, kB[i].z, b); b = fmaf(qf.w, kB[i].w, b);
      dB[i] = b;
    }
    #pragma unroll
    for (int m = 1; m <= 4; m <<= 1) {
      #pragma unroll
      for (int i = 0; i < 4; ++i) {
        dA[i] += __shfl_xor(dA[i], m);
        dB[i] += __shfl_xor(dB[i], m);
      }
    }

    float pA[4], pB[4], psum = 0.f;
    #pragma unroll
    for (int i = 0; i < 4; ++i) {
      pA[i] = __expf(dA[i] * 0.0625f);
      pB[i] = __expf(dB[i] * 0.0625f);
      psum += pA[i] + pB[i];
    }
    #pragma unroll
    for (int m = 8; m <= 32; m <<= 1) psum += __shfl_xor(psum, m);

    float ox = 0.f, oy = 0.f, oz = 0.f, ow = 0.f;
    #pragma unroll
    for (int i = 0; i < 4; ++i) {
      ox = fmaf(pA[i], kA[i].x, ox); oy = fmaf(pA[i], kA[i].y, oy);
      oz = fmaf(pA[i], kA[i].z, oz); ow = fmaf(pA[i], kA[i].w, ow);
      ox = fmaf(pB[i], kB[i].x, ox); oy = fmaf(pB[i], kB[i].y, oy);
      oz = fmaf(pB[i], kB[i].z, oz); ow = fmaf(pB[i], kB[i].w, ow);
    }
    #pragma unroll
    for (int m = 8; m <= 32; m <<= 1) {
      ox += __shfl_xor(ox, m);
      oy += __shfl_xor(oy, m);
      oz += __shfl_xor(oz, m);
      ow += __shfl_xor(ow, m);
    }

    const float inv = 1.0f / psum;
    if (ro == 0) {
      *(float4*)(out + (qg * 32 + qloc) * 256 + h * 32 + o * 4) =
          make_float4(ox * inv, oy * inv, oz * inv, ow * inv);
    }
  }
}

extern "C" void kernel_launch(void* const* d_in, const int* in_sizes, int n_in,
                              void* d_out, int out_size, void* d_ws, size_t ws_size,
                              hipStream_t stream) {
  const float* x = (const float*)d_in[0];   // (8192, 256) fp32; pos (d_in[1]) is dead code
  float* kmT = (float*)d_ws;                // 256 KB
  float* out = (float*)d_out;

  kmeanT_kernel<<<256, 256, 0, stream>>>(x, kmT);
  fused_kernel<<<2048, 256, 0, stream>>>(x, kmT, out);
}

// Round 23
// 57.317 us; speedup vs baseline: 1.0885x; 1.0070x over previous
//
#include <hip/hip_runtime.h>

#define FLT_BIG 3.402823466e38f

// tie-break matches jax.lax.top_k: higher value wins; equal values -> lower index wins
static __device__ __forceinline__ bool better(float v1, int i1, float v2, int i2) {
  return (v1 > v2) || ((v1 == v2) && (i1 < i2));
}

// XCD-aware bijective swizzle (8 XCDs; grid divisible by 8): consecutive logical
// blocks land on the SAME XCD -> shared kmT[h] / K tiles become L2 hits.
static __device__ __forceinline__ int xcd_swizzle(int nblocks) {
  const int bid = blockIdx.x;
  const int chunk = nblocks >> 3;           // blocks per XCD
  return (bid & 7) * chunk + (bid >> 3);
}

// kmT[h][e][n] = mean_j x[(n*32+j)*256 + h*32+e]  (transposed: ball is the fast axis)
// lane = (h, e-quad): float4 loads cover a full 1KB row per wave-instr; the 32
// member rows are split across 4 waves with an LDS partial reduce.
__global__ __launch_bounds__(256) void kmeanT_kernel(const float* __restrict__ x,
                                                     float* __restrict__ kmT) {
  __shared__ float4 part[4][64];
  const int n = blockIdx.x;            // ball
  const int t = threadIdx.x;
  const int w = t >> 6, lane = t & 63;
  const int h = lane >> 3, e4 = lane & 7;

  const float* base = x + n * 32 * 256 + h * 32 + e4 * 4;
  float4 a = make_float4(0.f, 0.f, 0.f, 0.f);
  #pragma unroll
  for (int j = 0; j < 8; ++j) {
    const float4 v = *(const float4*)(base + (w * 8 + j) * 256);
    a.x += v.x; a.y += v.y; a.z += v.z; a.w += v.w;
  }
  part[w][lane] = a;
  __syncthreads();

  if (t < 64) {
    float4 s = part[0][t];
    #pragma unroll
    for (int k = 1; k < 4; ++k) {
      const float4 v = part[k][t];
      s.x += v.x; s.y += v.y; s.z += v.z; s.w += v.w;
    }
    const int hh = t >> 3, ee = (t & 7) * 4;
    kmT[hh * 8192 + (ee + 0) * 256 + n] = s.x * (1.0f / 32.0f);
    kmT[hh * 8192 + (ee + 1) * 256 + n] = s.y * (1.0f / 32.0f);
    kmT[hh * 8192 + (ee + 2) * 256 + n] = s.z * (1.0f / 32.0f);
    kmT[hh * 8192 + (ee + 3) * 256 + n] = s.w * (1.0f / 32.0f);
  }
}

// Fused select+attn, block = (h, 32 queries) = one ball. BARRIER-FREE: the data
// flow is provably wave-local (staging writes rows t>>3 = wave's own 8 rows; P1
// reads only rows w*8..w*8+7; P2/P3 simbuf rows likewise; P4 uses __shfl). The
// r18-r22 __syncthreads re-locked the 4 waves into phase 3x per block, aligning
// their load-latency stalls; removing them lets waves de-phase and overlap.
//  P1: sim GEMM (coalesced kmT float4, reg ping-pong, LDS-broadcast q)
//  P2: sim tile -> simbuf (register-pressure relief; acc dies here)
//  P3: LDS top-2 scan + 3-stage shfl merge; result stays in a register (pk)
//  P4: attn per query: K fragments double as V; a ball's 32 queries select nearly
//      identical top-2 -> K tiles L1-hot after the first iteration.
// Mask provably all-true (topv2 >> 1e-10); softmax without max shift (|logit|<~5).
__global__ __launch_bounds__(256) void fused_kernel(const float* __restrict__ x,
                                                    const float* __restrict__ kmT,
                                                    float* __restrict__ out) {
  __shared__ float qtile[32 * 32];      // 4 KB, persistent through P4 (wave-local rows)
  __shared__ float simbuf[32 * 260];    // 33.3 KB (wave-local rows)
  const int vb = xcd_swizzle(2048);     // 2048 blocks = 8 heads x 256 q-groups
  const int h = vb >> 8;
  const int qg = vb & 255;
  const int t = threadIdx.x;
  const int w = t >> 6, lane = t & 63;

  // ---- stage the wave's 8 q-rows (coalesced, 8 lanes/row; rows t>>3 wave-local) ----
  {
    const int r = t >> 3, c = t & 7;
    *(float4*)&qtile[r * 32 + c * 4] =
        *(const float4*)(x + (qg * 32 + r) * 256 + h * 32 + c * 4);
  }
  // no barrier: P1 reads only this wave's rows; lgkmcnt ordering suffices

  // ---- P1: GEMM acc[qq][j] = q[w*8+qq] . km[4*lane+j] ----
  const float4* kmp = (const float4*)(kmT + h * 8192);   // [32 e][64 float4 over balls]
  float acc[8][4];
  #pragma unroll
  for (int qq = 0; qq < 8; ++qq)
    #pragma unroll
    for (int j = 0; j < 4; ++j) acc[qq][j] = 0.f;

  {
    float4 ka[4], kb[4];
    #pragma unroll
    for (int d = 0; d < 4; ++d) ka[d] = kmp[d * 64 + lane];

    #pragma unroll
    for (int e0 = 0; e0 < 8; ++e0) {               // e0 constant per unrolled iter
      float4* cur = (e0 & 1) ? kb : ka;
      float4* nxt = (e0 & 1) ? ka : kb;
      if (e0 < 7) {
        #pragma unroll
        for (int d = 0; d < 4; ++d) nxt[d] = kmp[((e0 + 1) * 4 + d) * 64 + lane];
      }
      #pragma unroll
      for (int qq = 0; qq < 8; ++qq) {
        const float4 qf = *(const float4*)&qtile[(w * 8 + qq) * 32 + e0 * 4];  // uniform
        acc[qq][0] = fmaf(qf.w, cur[3].x, fmaf(qf.z, cur[2].x, fmaf(qf.y, cur[1].x, fmaf(qf.x, cur[0].x, acc[qq][0]))));
        acc[qq][1] = fmaf(qf.w, cur[3].y, fmaf(qf.z, cur[2].y, fmaf(qf.y, cur[1].y, fmaf(qf.x, cur[0].y, acc[qq][1]))));
        acc[qq][2] = fmaf(qf.w, cur[3].z, fmaf(qf.z, cur[2].z, fmaf(qf.y, cur[1].z, fmaf(qf.x, cur[0].z, acc[qq][2]))));
        acc[qq][3] = fmaf(qf.w, cur[3].w, fmaf(qf.z, cur[2].w, fmaf(qf.y, cur[1].w, fmaf(qf.x, cur[0].w, acc[qq][3]))));
      }
    }
  }

  // ---- P2: sim tile -> simbuf rows w*8..w*8+7 (wave-local); acc dies here ----
  #pragma unroll
  for (int qq = 0; qq < 8; ++qq) {
    *(float4*)&simbuf[(w * 8 + qq) * 260 + lane * 4] =
        make_float4(acc[qq][0], acc[qq][1], acc[qq][2], acc[qq][3]);
  }
  // no barrier: P3's thread t scans row t>>3, which this wave just wrote

  // ---- P3: top-2 scan (thread = (qloc = t>>3, ch = t&7), 32 values) + merge ----
  int pk;
  {
    const int qloc = t >> 3, ch = t & 7;
    const float* rowp = &simbuf[qloc * 260 + ch * 32];
    float a1 = -FLT_BIG, a2 = -FLT_BIG;
    int j1 = 0, j2 = 0;
    #pragma unroll
    for (int i = 0; i < 8; ++i) {
      const float4 v4 = *(const float4*)(rowp + i * 4);
      const int b0 = ch * 32 + i * 4;
      // ascending-index scan: strict > is tie-exact (later index loses ties)
      if (v4.x > a1) { a2 = a1; j2 = j1; a1 = v4.x; j1 = b0; }
      else if (v4.x > a2) { a2 = v4.x; j2 = b0; }
      if (v4.y > a1) { a2 = a1; j2 = j1; a1 = v4.y; j1 = b0 + 1; }
      else if (v4.y > a2) { a2 = v4.y; j2 = b0 + 1; }
      if (v4.z > a1) { a2 = a1; j2 = j1; a1 = v4.z; j1 = b0 + 2; }
      else if (v4.z > a2) { a2 = v4.z; j2 = b0 + 2; }
      if (v4.w > a1) { a2 = a1; j2 = j1; a1 = v4.w; j1 = b0 + 3; }
      else if (v4.w > a2) { a2 = v4.w; j2 = b0 + 3; }
    }

    pk = j1 | (j2 << 16);
    #pragma unroll
    for (int m = 1; m <= 4; m <<= 1) {
      const float b1 = __shfl_xor(a1, m);
      const float b2 = __shfl_xor(a2, m);
      const int bpk = __shfl_xor(pk, m);
      const int bj1 = bpk & 65535, bj2 = bpk >> 16;
      int c1 = pk & 65535, c2 = pk >> 16;
      if (better(b1, bj1, a1, c1)) {
        if (better(a1, c1, b2, bj2)) { a2 = a1; c2 = c1; } else { a2 = b2; c2 = bj2; }
        a1 = b1; c1 = bj1;
      } else if (better(b1, bj1, a2, c2)) { a2 = b1; c2 = bj1; }
      pk = c1 | (c2 << 16);
    }
    // all 8 ch-lanes of query qloc now hold the merged pk
  }

  // ---- P4: attention; wave w handles queries w*8..w*8+7 (r11-proven body) ----
  const int o = lane & 7;
  const int ro = lane >> 3;
  #pragma unroll 1
  for (int qq = 0; qq < 8; ++qq) {
    const int qloc = w * 8 + qq;
    const int pkq = __shfl(pk, qq * 8);        // broadcast query qq's top-2
    const int bA = pkq & 65535, bB = pkq >> 16;
    const float4 qf = *(const float4*)&qtile[qloc * 32 + o * 4];

    float4 kA[4], kB[4];
    const float* xa = x + bA * 8192 + ro * 256 + h * 32 + o * 4;
    const float* xb = x + bB * 8192 + ro * 256 + h * 32 + o * 4;
    #pragma unroll
    for (int i = 0; i < 4; ++i) {
      kA[i] = *(const float4*)(xa + i * 2048);
      kB[i] = *(const float4*)(xb + i * 2048);
    }

    float dA[4], dB[4];
    #pragma unroll
    for (int i = 0; i < 4; ++i) {
      float a = qf.x * kA[i].x; a = fmaf(qf.y, kA[i].y, a);
      a = fmaf(qf.z, kA[i].z, a); a = fmaf(qf.w, kA[i].w, a);
      dA[i] = a;
      float b = qf.x * kB[i].x; b = fmaf(qf.y, kB[i].y, b);
      b = fmaf(qf.z, kB[i].z, b); b = fmaf(qf.w, kB[i].w, b);
      dB[i] = b;
    }
    #pragma unroll
    for (int m = 1; m <= 4; m <<= 1) {
      #pragma unroll
      for (int i = 0; i < 4; ++i) {
        dA[i] += __shfl_xor(dA[i], m);
        dB[i] += __shfl_xor(dB[i], m);
      }
    }

    float pA[4], pB[4], psum = 0.f;
    #pragma unroll
    for (int i = 0; i < 4; ++i) {
      pA[i] = __expf(dA[i] * 0.0625f);
      pB[i] = __expf(dB[i] * 0.0625f);
      psum += pA[i] + pB[i];
    }
    #pragma unroll
    for (int m = 8; m <= 32; m <<= 1) psum += __shfl_xor(psum, m);

    float ox = 0.f, oy = 0.f, oz = 0.f, ow = 0.f;
    #pragma unroll
    for (int i = 0; i < 4; ++i) {
      ox = fmaf(pA[i], kA[i].x, ox); oy = fmaf(pA[i], kA[i].y, oy);
      oz = fmaf(pA[i], kA[i].z, oz); ow = fmaf(pA[i], kA[i].w, ow);
      ox = fmaf(pB[i], kB[i].x, ox); oy = fmaf(pB[i], kB[i].y, oy);
      oz = fmaf(pB[i], kB[i].z, oz); ow = fmaf(pB[i], kB[i].w, ow);
    }
    #pragma unroll
    for (int m = 8; m <= 32; m <<= 1) {
      ox += __shfl_xor(ox, m);
      oy += __shfl_xor(oy, m);
      oz += __shfl_xor(oz, m);
      ow += __shfl_xor(ow, m);
    }

    const float inv = 1.0f / psum;
    if (ro == 0) {
      *(float4*)(out + (qg * 32 + qloc) * 256 + h * 32 + o * 4) =
          make_float4(ox * inv, oy * inv, oz * inv, ow * inv);
    }
  }
}

extern "C" void kernel_launch(void* const* d_in, const int* in_sizes, int n_in,
                              void* d_out, int out_size, void* d_ws, size_t ws_size,
                              hipStream_t stream) {
  const float* x = (const float*)d_in[0];   // (8192, 256) fp32; pos (d_in[1]) is dead code
  float* kmT = (float*)d_ws;                // 256 KB
  float* out = (float*)d_out;

  kmeanT_kernel<<<256, 256, 0, stream>>>(x, kmT);
  fused_kernel<<<2048, 256, 0, stream>>>(x, kmT, out);
}

// Round 24
// 51.831 us; speedup vs baseline: 1.2037x; 1.1058x over previous
//
#include <hip/hip_runtime.h>

#define FLT_BIG 3.402823466e38f

// tie-break matches jax.lax.top_k: higher value wins; equal values -> lower index wins
static __device__ __forceinline__ bool better(float v1, int i1, float v2, int i2) {
  return (v1 > v2) || ((v1 == v2) && (i1 < i2));
}

// XCD-aware bijective swizzle (8 XCDs; grid divisible by 8): consecutive logical
// blocks land on the SAME XCD -> shared kmT[h] / K tiles become L2 hits.
static __device__ __forceinline__ int xcd_swizzle(int nblocks) {
  const int bid = blockIdx.x;
  const int chunk = nblocks >> 3;           // blocks per XCD
  return (bid & 7) * chunk + (bid >> 3);
}

// kmT[h][e][n] = mean_j x[(n*32+j)*256 + h*32+e]  (transposed: ball is the fast axis)
__global__ __launch_bounds__(256) void kmeanT_kernel(const float* __restrict__ x,
                                                     float* __restrict__ kmT) {
  __shared__ float4 part[4][64];
  const int n = blockIdx.x;            // ball
  const int t = threadIdx.x;
  const int w = t >> 6, lane = t & 63;
  const int h = lane >> 3, e4 = lane & 7;

  const float* base = x + n * 32 * 256 + h * 32 + e4 * 4;
  float4 a = make_float4(0.f, 0.f, 0.f, 0.f);
  #pragma unroll
  for (int j = 0; j < 8; ++j) {
    const float4 v = *(const float4*)(base + (w * 8 + j) * 256);
    a.x += v.x; a.y += v.y; a.z += v.z; a.w += v.w;
  }
  part[w][lane] = a;
  __syncthreads();

  if (t < 64) {
    float4 s = part[0][t];
    #pragma unroll
    for (int k = 1; k < 4; ++k) {
      const float4 v = part[k][t];
      s.x += v.x; s.y += v.y; s.z += v.z; s.w += v.w;
    }
    const int hh = t >> 3, ee = (t & 7) * 4;
    kmT[hh * 8192 + (ee + 0) * 256 + n] = s.x * (1.0f / 32.0f);
    kmT[hh * 8192 + (ee + 1) * 256 + n] = s.y * (1.0f / 32.0f);
    kmT[hh * 8192 + (ee + 2) * 256 + n] = s.z * (1.0f / 32.0f);
    kmT[hh * 8192 + (ee + 3) * 256 + n] = s.w * (1.0f / 32.0f);
  }
}

// Fused select+attn, block = (h, 32 queries) = one ball. Barrier-free (r23: data
// flow provably wave-local). P4 v2: TWO queries per wave concurrently — lanes
// 0-31 own query 2p, lanes 32-63 own 2p+1. Same instruction totals as r23's P4,
// but the serial load->dot->shfl->exp->shfl->PV->shfl chain is traversed 4x
// instead of 8x (r19-r23 proved occupancy/ILP/barriers are null levers; the
// invariant 55% stall is this chain).
__global__ __launch_bounds__(256) void fused_kernel(const float* __restrict__ x,
                                                    const float* __restrict__ kmT,
                                                    float* __restrict__ out) {
  __shared__ float qtile[32 * 32];      // 4 KB, persistent through P4 (wave-local rows)
  __shared__ float simbuf[32 * 260];    // 33.3 KB (wave-local rows)
  const int vb = xcd_swizzle(2048);     // 2048 blocks = 8 heads x 256 q-groups
  const int h = vb >> 8;
  const int qg = vb & 255;
  const int t = threadIdx.x;
  const int w = t >> 6, lane = t & 63;

  // ---- stage the wave's 8 q-rows (coalesced, 8 lanes/row; rows t>>3 wave-local) ----
  {
    const int r = t >> 3, c = t & 7;
    *(float4*)&qtile[r * 32 + c * 4] =
        *(const float4*)(x + (qg * 32 + r) * 256 + h * 32 + c * 4);
  }

  // ---- P1: GEMM acc[qq][j] = q[w*8+qq] . km[4*lane+j] ----
  const float4* kmp = (const float4*)(kmT + h * 8192);   // [32 e][64 float4 over balls]
  float acc[8][4];
  #pragma unroll
  for (int qq = 0; qq < 8; ++qq)
    #pragma unroll
    for (int j = 0; j < 4; ++j) acc[qq][j] = 0.f;

  {
    float4 ka[4], kb[4];
    #pragma unroll
    for (int d = 0; d < 4; ++d) ka[d] = kmp[d * 64 + lane];

    #pragma unroll
    for (int e0 = 0; e0 < 8; ++e0) {               // e0 constant per unrolled iter
      float4* cur = (e0 & 1) ? kb : ka;
      float4* nxt = (e0 & 1) ? ka : kb;
      if (e0 < 7) {
        #pragma unroll
        for (int d = 0; d < 4; ++d) nxt[d] = kmp[((e0 + 1) * 4 + d) * 64 + lane];
      }
      #pragma unroll
      for (int qq = 0; qq < 8; ++qq) {
        const float4 qf = *(const float4*)&qtile[(w * 8 + qq) * 32 + e0 * 4];  // uniform
        acc[qq][0] = fmaf(qf.w, cur[3].x, fmaf(qf.z, cur[2].x, fmaf(qf.y, cur[1].x, fmaf(qf.x, cur[0].x, acc[qq][0]))));
        acc[qq][1] = fmaf(qf.w, cur[3].y, fmaf(qf.z, cur[2].y, fmaf(qf.y, cur[1].y, fmaf(qf.x, cur[0].y, acc[qq][1]))));
        acc[qq][2] = fmaf(qf.w, cur[3].z, fmaf(qf.z, cur[2].z, fmaf(qf.y, cur[1].z, fmaf(qf.x, cur[0].z, acc[qq][2]))));
        acc[qq][3] = fmaf(qf.w, cur[3].w, fmaf(qf.z, cur[2].w, fmaf(qf.y, cur[1].w, fmaf(qf.x, cur[0].w, acc[qq][3]))));
      }
    }
  }

  // ---- P2: sim tile -> simbuf rows w*8..w*8+7 (wave-local); acc dies here ----
  #pragma unroll
  for (int qq = 0; qq < 8; ++qq) {
    *(float4*)&simbuf[(w * 8 + qq) * 260 + lane * 4] =
        make_float4(acc[qq][0], acc[qq][1], acc[qq][2], acc[qq][3]);
  }

  // ---- P3: top-2 scan (thread = (qloc = t>>3, ch = t&7), 32 values) + merge ----
  int pk;
  {
    const int qloc = t >> 3, ch = t & 7;
    const float* rowp = &simbuf[qloc * 260 + ch * 32];
    float a1 = -FLT_BIG, a2 = -FLT_BIG;
    int j1 = 0, j2 = 0;
    #pragma unroll
    for (int i = 0; i < 8; ++i) {
      const float4 v4 = *(const float4*)(rowp + i * 4);
      const int b0 = ch * 32 + i * 4;
      // ascending-index scan: strict > is tie-exact (later index loses ties)
      if (v4.x > a1) { a2 = a1; j2 = j1; a1 = v4.x; j1 = b0; }
      else if (v4.x > a2) { a2 = v4.x; j2 = b0; }
      if (v4.y > a1) { a2 = a1; j2 = j1; a1 = v4.y; j1 = b0 + 1; }
      else if (v4.y > a2) { a2 = v4.y; j2 = b0 + 1; }
      if (v4.z > a1) { a2 = a1; j2 = j1; a1 = v4.z; j1 = b0 + 2; }
      else if (v4.z > a2) { a2 = v4.z; j2 = b0 + 2; }
      if (v4.w > a1) { a2 = a1; j2 = j1; a1 = v4.w; j1 = b0 + 3; }
      else if (v4.w > a2) { a2 = v4.w; j2 = b0 + 3; }
    }

    pk = j1 | (j2 << 16);
    #pragma unroll
    for (int m = 1; m <= 4; m <<= 1) {
      const float b1 = __shfl_xor(a1, m);
      const float b2 = __shfl_xor(a2, m);
      const int bpk = __shfl_xor(pk, m);
      const int bj1 = bpk & 65535, bj2 = bpk >> 16;
      int c1 = pk & 65535, c2 = pk >> 16;
      if (better(b1, bj1, a1, c1)) {
        if (better(a1, c1, b2, bj2)) { a2 = a1; c2 = c1; } else { a2 = b2; c2 = bj2; }
        a1 = b1; c1 = bj1;
      } else if (better(b1, bj1, a2, c2)) { a2 = b1; c2 = bj1; }
      pk = c1 | (c2 << 16);
    }
    // pk for local query ql lives (replicated) in lanes ql*8 + 0..7
  }

  // ---- P4 v2: two queries in flight; 32-lane half per query ----
  const int o = lane & 7;              // 16B chunk within row
  const int qp = lane >> 5;            // which query of the pair this half owns
  const int ro4 = (lane >> 3) & 3;     // row group within the half
  #pragma unroll 1
  for (int pair = 0; pair < 4; ++pair) {
    const int ql = pair * 2 + qp;              // local query 0..7 (per half)
    const int qloc = w * 8 + ql;
    const int pkq = __shfl(pk, ql * 8);        // per-lane src: bpermute broadcast
    const int bA = pkq & 65535, bB = pkq >> 16;
    const float4 qf = *(const float4*)&qtile[qloc * 32 + o * 4];

    // rows i*4 + ro4, i = 0..7 -> 8 float4 per ball per lane
    float4 kA[8], kB[8];
    const float* xa = x + bA * 8192 + ro4 * 256 + h * 32 + o * 4;
    const float* xb = x + bB * 8192 + ro4 * 256 + h * 32 + o * 4;
    #pragma unroll
    for (int i = 0; i < 8; ++i) {
      kA[i] = *(const float4*)(xa + i * 1024);
      kB[i] = *(const float4*)(xb + i * 1024);
    }

    float dA[8], dB[8];
    #pragma unroll
    for (int i = 0; i < 8; ++i) {
      float a = qf.x * kA[i].x; a = fmaf(qf.y, kA[i].y, a);
      a = fmaf(qf.z, kA[i].z, a); a = fmaf(qf.w, kA[i].w, a);
      dA[i] = a;
      float b = qf.x * kB[i].x; b = fmaf(qf.y, kB[i].y, b);
      b = fmaf(qf.z, kB[i].z, b); b = fmaf(qf.w, kB[i].w, b);
      dB[i] = b;
    }
    // finish dots across the 8 o-lanes (xor 1/2/4 stays within the half)
    #pragma unroll
    for (int m = 1; m <= 4; m <<= 1) {
      #pragma unroll
      for (int i = 0; i < 8; ++i) {
        dA[i] += __shfl_xor(dA[i], m);
        dB[i] += __shfl_xor(dB[i], m);
      }
    }

    // p = exp(logit) in place; psum reduce over ro4 (xor 8/16, within the half)
    float psum = 0.f;
    #pragma unroll
    for (int i = 0; i < 8; ++i) {
      dA[i] = __expf(dA[i] * 0.0625f);
      dB[i] = __expf(dB[i] * 0.0625f);
      psum += dA[i] + dB[i];
    }
    #pragma unroll
    for (int m = 8; m <= 16; m <<= 1) psum += __shfl_xor(psum, m);

    // PV from registers; reduce over ro4 lanes
    float ox = 0.f, oy = 0.f, oz = 0.f, ow = 0.f;
    #pragma unroll
    for (int i = 0; i < 8; ++i) {
      ox = fmaf(dA[i], kA[i].x, ox); oy = fmaf(dA[i], kA[i].y, oy);
      oz = fmaf(dA[i], kA[i].z, oz); ow = fmaf(dA[i], kA[i].w, ow);
      ox = fmaf(dB[i], kB[i].x, ox); oy = fmaf(dB[i], kB[i].y, oy);
      oz = fmaf(dB[i], kB[i].z, oz); ow = fmaf(dB[i], kB[i].w, ow);
    }
    #pragma unroll
    for (int m = 8; m <= 16; m <<= 1) {
      ox += __shfl_xor(ox, m);
      oy += __shfl_xor(oy, m);
      oz += __shfl_xor(oz, m);
      ow += __shfl_xor(ow, m);
    }

    const float inv = 1.0f / psum;
    if (ro4 == 0) {
      *(float4*)(out + (qg * 32 + qloc) * 256 + h * 32 + o * 4) =
          make_float4(ox * inv, oy * inv, oz * inv, ow * inv);
    }
  }
}

extern "C" void kernel_launch(void* const* d_in, const int* in_sizes, int n_in,
                              void* d_out, int out_size, void* d_ws, size_t ws_size,
                              hipStream_t stream) {
  const float* x = (const float*)d_in[0];   // (8192, 256) fp32; pos (d_in[1]) is dead code
  float* kmT = (float*)d_ws;                // 256 KB
  float* out = (float*)d_out;

  kmeanT_kernel<<<256, 256, 0, stream>>>(x, kmT);
  fused_kernel<<<2048, 256, 0, stream>>>(x, kmT, out);
}